// Round 14
// baseline (955.473 us; speedup 1.0000x reference)
//
#include <hip/hip_runtime.h>

#define N_USERS 100000
#define N_ITEMS 50000
#define N_TOTAL 150000
#define F 64
#define NNZ 4800000
#define BATCH 16384
#define SCAN_CHUNK 1024
#define SCAN_BLOCKS ((N_TOTAL + SCAN_CHUNK - 1) / SCAN_CHUNK)   // 147
#define FILL_GROUPS 8                                           // = XCD count
#define FILL_BPG 256                                            // blocks per group
#define ROWS_PER_GROUP ((N_TOTAL + FILL_GROUPS - 1) / FILL_GROUPS)  // 18750

// ---------------- CSR build ----------------

// int4-vectorized histogram: 4 edges per thread-iteration.
__global__ __launch_bounds__(256) void hist_kernel(
    const int4* __restrict__ row4, int* __restrict__ deg)
{
    int i = blockIdx.x * 256 + threadIdx.x;
    const int stride = gridDim.x * 256;
    for (; i < NNZ / 4; i += stride) {
        const int4 r = row4[i];
        atomicAdd(&deg[r.x], 1);
        atomicAdd(&deg[r.y], 1);
        atomicAdd(&deg[r.z], 1);
        atomicAdd(&deg[r.w], 1);
    }
}

// Parallel scan, phase A: per-chunk sums. 147 blocks x 256 threads.
__global__ __launch_bounds__(256) void scanA(
    const int* __restrict__ deg, int* __restrict__ blockSum)
{
    __shared__ int red[256];
    const int b = blockIdx.x, t = threadIdx.x;
    const int base = b * SCAN_CHUNK;
    int s = 0;
    #pragma unroll
    for (int k = 0; k < 4; ++k) {
        const int i = base + t + k * 256;      // coalesced
        if (i < N_TOTAL) s += deg[i];
    }
    red[t] = s;
    __syncthreads();
    for (int off = 128; off > 0; off >>= 1) {
        if (t < off) red[t] += red[t + off];
        __syncthreads();
    }
    if (t == 0) blockSum[b] = red[0];
}

// Phase B: exclusive scan of the 147 block sums, in place. One tiny block.
__global__ __launch_bounds__(256) void scanB(int* __restrict__ blockSum)
{
    __shared__ int sh[256];
    const int t = threadIdx.x;
    const int v = (t < SCAN_BLOCKS) ? blockSum[t] : 0;
    sh[t] = v;
    __syncthreads();
    for (int off = 1; off < 256; off <<= 1) {
        const int u = (t >= off) ? sh[t - off] : 0;
        __syncthreads();
        sh[t] += u;
        __syncthreads();
    }
    if (t < SCAN_BLOCKS) blockSum[t] = sh[t] - v;   // exclusive
}

// Phase C: per-chunk local exclusive scan + chunk offset -> row_ptr, cursor.
__global__ __launch_bounds__(256) void scanC(
    const int* __restrict__ deg, const int* __restrict__ blockOff,
    int* __restrict__ row_ptr, int* __restrict__ cursor)
{
    __shared__ int sh[256];
    const int b = blockIdx.x, t = threadIdx.x;
    const int lo = b * SCAN_CHUNK + t * 4;
    int d0 = 0, d1 = 0, d2 = 0, d3 = 0;
    if (lo + 0 < N_TOTAL) d0 = deg[lo + 0];
    if (lo + 1 < N_TOTAL) d1 = deg[lo + 1];
    if (lo + 2 < N_TOTAL) d2 = deg[lo + 2];
    if (lo + 3 < N_TOTAL) d3 = deg[lo + 3];
    const int s = d0 + d1 + d2 + d3;
    sh[t] = s;
    __syncthreads();
    for (int off = 1; off < 256; off <<= 1) {
        const int u = (t >= off) ? sh[t - off] : 0;
        __syncthreads();
        sh[t] += u;
        __syncthreads();
    }
    int p = blockOff[b] + sh[t] - s;   // exclusive prefix for this thread's 4
    if (lo + 0 < N_TOTAL) { row_ptr[lo + 0] = p; cursor[lo + 0] = p; p += d0; }
    if (lo + 1 < N_TOTAL) { row_ptr[lo + 1] = p; cursor[lo + 1] = p; p += d1; }
    if (lo + 2 < N_TOTAL) { row_ptr[lo + 2] = p; cursor[lo + 2] = p; p += d2; }
    if (lo + 3 < N_TOTAL) { row_ptr[lo + 3] = p; cursor[lo + 3] = p; p += d3; }
    if (b == 0 && t == 0) row_ptr[N_TOTAL] = NNZ;
}

// XCD-range-partitioned fill: blocks with blockIdx&7==g handle only rows in
// range g (18750 rows -> ~4.8 MB contiguous CSR window, L2-resident on one
// XCD under round-robin dispatch). Each group scans the full edge stream;
// col/vals are only loaded for in-range edges. Correct for ANY block->XCD
// mapping; the swizzle only affects locality.
__global__ __launch_bounds__(256) void fill_kernel(
    const int* __restrict__ row, const int* __restrict__ col,
    const float* __restrict__ vals, int* __restrict__ cursor,
    int2* __restrict__ csr)
{
    const int g   = blockIdx.x & (FILL_GROUPS - 1);
    const int gb  = blockIdx.x >> 3;                 // block index within group
    const int rlo = g * ROWS_PER_GROUP;
    const int rhi = min(rlo + ROWS_PER_GROUP, N_TOTAL);
    const int stride = FILL_BPG * 256;               // 65536 threads per group
    for (int i = gb * 256 + threadIdx.x; i < NNZ; i += stride) {
        const int r = row[i];
        if (r >= rlo && r < rhi) {
            const int p = atomicAdd(&cursor[r], 1);
            csr[p] = make_int2(col[i], __float_as_int(vals[i]));
        }
    }
}

// Assign compact indices to the (deduped) queried rows.
__global__ __launch_bounds__(256) void assign_kernel(
    const int* __restrict__ users, const int* __restrict__ items,
    int* __restrict__ remap, int* __restrict__ list, int* __restrict__ counter)
{
    const int i = blockIdx.x * 256 + threadIdx.x;
    if (i >= 2 * BATCH) return;
    const int r = (i < BATCH) ? users[i] : (N_USERS + items[i - BATCH]);
    if (atomicCAS(&remap[r], -1, -2) == -1) {
        const int idx = atomicAdd(counter, 1);
        list[idx] = r;
        remap[r]  = idx;   // nobody reads remap until later kernels
    }
}

// ---------------- pull-style SpMM ----------------

// One wave computes one row: p[lane] = sum_e val_e * src[col_e][lane].
// Edge list loaded wave-wide (zero-padded), then broadcast via readlane
// (SGPR path, NO ds_bpermute) in statically-unrolled chunks of 16.
__device__ __forceinline__ float spmm_row(
    const int2* __restrict__ csr, int start, int end,
    const float* __restrict__ src, int lane)
{
    float p = 0.f;
    for (int base = start; base < end; base += 64) {
        int2 cv = make_int2(0, 0);
        if (base + lane < end) cv = csr[base + lane];
        const int cnt = min(64, end - base);
        for (int ch = 0; ch < cnt; ch += 16) {
            #pragma unroll
            for (int j = 0; j < 16; ++j) {
                const int   c = __builtin_amdgcn_readlane(cv.x, ch + j);
                const float v = __int_as_float(__builtin_amdgcn_readlane(cv.y, ch + j));
                p = fmaf(v, src[(size_t)c * F + lane], p);
            }
        }
    }
    return p;
}

__global__ __launch_bounds__(256) void spmm_layer(
    const int* __restrict__ row_ptr, const int2* __restrict__ csr,
    const float* __restrict__ src, float* __restrict__ dst)
{
    const int r    = blockIdx.x * 4 + (threadIdx.x >> 6);
    const int lane = threadIdx.x & 63;
    if (r >= N_TOTAL) return;
    const float p = spmm_row(csr, row_ptr[r], row_ptr[r + 1], src, lane);
    dst[(size_t)r * F + lane] = p;
}

// Layer 2 + fused epilogue: accC[remap[r]] = e0[r] + e1[r] for queried rows.
__global__ __launch_bounds__(256) void spmm_layer2(
    const int* __restrict__ row_ptr, const int2* __restrict__ csr,
    const float* __restrict__ src /*e1*/, float* __restrict__ dst /*e2*/,
    const float* __restrict__ uw, const float* __restrict__ iw,
    const int* __restrict__ remap, float* __restrict__ accC)
{
    const int r    = blockIdx.x * 4 + (threadIdx.x >> 6);
    const int lane = threadIdx.x & 63;
    if (r >= N_TOTAL) return;
    const float p = spmm_row(csr, row_ptr[r], row_ptr[r + 1], src, lane);
    dst[(size_t)r * F + lane] = p;
    const int idx = remap[r];
    if (idx >= 0) {
        const float e0 = (r < N_USERS) ? uw[(size_t)r * F + lane]
                                       : iw[(size_t)(r - N_USERS) * F + lane];
        accC[(size_t)idx * F + lane] = e0 + src[(size_t)r * F + lane];
    }
}

// Layer 3: ONLY queried rows. accC[idx] += e2[r] + spmm_row(e2).
__global__ __launch_bounds__(256) void spmm_layer3(
    const int* __restrict__ row_ptr, const int2* __restrict__ csr,
    const float* __restrict__ src /*e2*/, const int* __restrict__ list,
    const int* __restrict__ counter, float* __restrict__ accC)
{
    const int idx  = blockIdx.x * 4 + (threadIdx.x >> 6);
    const int lane = threadIdx.x & 63;
    if (idx >= *counter) return;
    const int r = list[idx];
    const float p = spmm_row(csr, row_ptr[r], row_ptr[r + 1], src, lane);
    accC[(size_t)idx * F + lane] += src[(size_t)r * F + lane] + p;
}

// out[b] = dot(acc[u], acc[i]) / 16   (each side's /4 folded together)
__global__ __launch_bounds__(256) void batch_dot(
    const float* __restrict__ accC, const int* __restrict__ remap,
    const int* __restrict__ users, const int* __restrict__ items,
    float* __restrict__ out)
{
    const int b    = blockIdx.x * 4 + (threadIdx.x >> 6);
    const int lane = threadIdx.x & 63;
    if (b >= BATCH) return;
    const int iu = remap[users[b]];
    const int ii = remap[N_USERS + items[b]];
    float p = accC[(size_t)iu * F + lane] * accC[(size_t)ii * F + lane];
    #pragma unroll
    for (int off = 32; off > 0; off >>= 1) p += __shfl_down(p, off, 64);
    if (lane == 0) out[b] = p * (1.0f / 16.0f);
}

// ---------------- launch ----------------

extern "C" void kernel_launch(void* const* d_in, const int* in_sizes, int n_in,
                              void* d_out, int out_size, void* d_ws, size_t ws_size,
                              hipStream_t stream)
{
    const float* user_w   = (const float*)d_in[0];
    const float* item_w   = (const float*)d_in[1];
    const float* adj_vals = (const float*)d_in[2];
    const int*   adj_row  = (const int*)d_in[3];
    const int*   adj_col  = (const int*)d_in[4];
    const int*   users    = (const int*)d_in[5];
    const int*   items    = (const int*)d_in[6];
    float*       out      = (float*)d_out;

    const size_t embB  = (size_t)N_TOTAL * F * sizeof(float);   // 38.4 MB
    const size_t csrB  = (size_t)NNZ * sizeof(int2);            // 38.4 MB
    const size_t rpB   = ((size_t)(N_TOTAL + 1) * 4 + 255) & ~(size_t)255;
    const size_t curB  = ((size_t)N_TOTAL * 4 + 255) & ~(size_t)255;
    const size_t rmB   = curB;
    const size_t listB = (size_t)2 * BATCH * 4;                 // 128 KB
    const size_t cntB  = 256;
    const size_t bsB   = ((size_t)SCAN_BLOCKS * 4 + 255) & ~(size_t)255;
    const size_t accB  = (size_t)2 * BATCH * F * sizeof(float); // 8 MB

    const size_t need = 2 * embB + csrB + rpB + curB + rmB + listB + cntB + bsB + accB;
    if (ws_size < need) {   // defensive: fail visibly, never write OOB
        hipMemsetAsync(d_out, 0, (size_t)out_size * sizeof(float), stream);
        return;
    }

    char* w = (char*)d_ws;
    float* eA       = (float*)w;  w += embB;   // e0 then e2
    float* eB       = (float*)w;  w += embB;   // e1
    int2*  csr      = (int2*)w;   w += csrB;
    int*   row_ptr  = (int*)w;    w += rpB;
    int*   cursor   = (int*)w;    w += curB;   // deg, then fill cursor
    int*   remap    = (int*)w;    w += rmB;
    int*   list     = (int*)w;    w += listB;
    int*   counter  = (int*)w;    w += cntB;
    int*   blockSum = (int*)w;    w += bsB;
    float* accC     = (float*)w;  w += accB;

    // init (ws is poisoned 0xAA before every call)
    hipMemsetAsync(cursor, 0, curB, stream);
    hipMemsetAsync(remap, 0xFF, rmB, stream);          // -1
    hipMemsetAsync(counter, 0, 4, stream);

    // CSR build: hist -> 3-phase parallel scan -> XCD-partitioned fill
    hist_kernel<<<2048, 256, 0, stream>>>((const int4*)adj_row, cursor);
    scanA<<<SCAN_BLOCKS, 256, 0, stream>>>(cursor, blockSum);
    scanB<<<1, 256, 0, stream>>>(blockSum);
    scanC<<<SCAN_BLOCKS, 256, 0, stream>>>(cursor, blockSum, row_ptr, cursor);
    // scanC writes cursor[i] AFTER reading deg from the same buffer: each
    // thread reads its 4 deg values into registers before any writes.
    fill_kernel<<<FILL_GROUPS * FILL_BPG, 256, 0, stream>>>(
        adj_row, adj_col, adj_vals, cursor, csr);
    assign_kernel<<<(2 * BATCH + 255) / 256, 256, 0, stream>>>(users, items, remap, list, counter);

    // e0 = concat(user_w, item_w)
    hipMemcpyAsync(eA, user_w, (size_t)N_USERS * F * sizeof(float),
                   hipMemcpyDeviceToDevice, stream);
    hipMemcpyAsync(eA + (size_t)N_USERS * F, item_w, (size_t)N_ITEMS * F * sizeof(float),
                   hipMemcpyDeviceToDevice, stream);

    const int rows_blocks = (N_TOTAL + 3) / 4;   // 4 rows (waves) per block
    // L1: e1 = A @ e0
    spmm_layer <<<rows_blocks, 256, 0, stream>>>(row_ptr, csr, eA, eB);
    // L2: e2 = A @ e1 (into eA), fused accC = e0 + e1 at queried rows
    spmm_layer2<<<rows_blocks, 256, 0, stream>>>(row_ptr, csr, eB, eA,
                                                 user_w, item_w, remap, accC);
    // L3: queried rows only; accC += e2 + A @ e2
    spmm_layer3<<<(2 * BATCH + 3) / 4, 256, 0, stream>>>(row_ptr, csr, eA, list, counter, accC);

    batch_dot<<<(BATCH + 3) / 4, 256, 0, stream>>>(accC, remap, users, items, out);
}

// Round 15
// 672.025 us; speedup vs baseline: 1.4218x; 1.4218x over previous
//
#include <hip/hip_runtime.h>

#define N_USERS 100000
#define N_ITEMS 50000
#define N_TOTAL 150000
#define F 64
#define NNZ 4800000
#define BATCH 16384

#define BUCKETS 600            // row buckets; RPB rows each
#define RPB 250                // N_TOTAL / BUCKETS exactly
#define CHUNK 4800             // edges per bucketize block (LDS-stageable)
#define NCHUNKS (NNZ / CHUNK)  // 1000
#define COLMASK 0x3FFFF        // 18 bits: col < 150000 < 2^18

// ---------------- CSR build: 2-level bucket sort ----------------

// H1: per-block LDS histogram over 600 buckets -> one global atomic per bin.
__global__ __launch_bounds__(256) void histo(
    const int* __restrict__ row, int* __restrict__ binTotal)
{
    __shared__ int h[BUCKETS];
    const int t = threadIdx.x;
    for (int b = t; b < BUCKETS; b += 256) h[b] = 0;
    __syncthreads();
    const int base = blockIdx.x * CHUNK;
    for (int k = t; k < CHUNK; k += 256)
        atomicAdd(&h[row[base + k] / RPB], 1);
    __syncthreads();
    for (int b = t; b < BUCKETS; b += 256)
        if (h[b]) atomicAdd(&binTotal[b], h[b]);
}

// H2: exclusive scan of 600 bin totals -> bucketBase[601], bucketCursor[600].
__global__ __launch_bounds__(256) void scan_bins(
    const int* __restrict__ binTotal,
    int* __restrict__ bucketBase, int* __restrict__ bucketCursor)
{
    __shared__ int tmp[256];
    const int t = threadIdx.x;
    const int lo = t * 3;                       // 3 slots per thread (600<=768)
    int d0 = 0, d1 = 0, d2 = 0;
    if (lo + 0 < BUCKETS) d0 = binTotal[lo + 0];
    if (lo + 1 < BUCKETS) d1 = binTotal[lo + 1];
    if (lo + 2 < BUCKETS) d2 = binTotal[lo + 2];
    const int s = d0 + d1 + d2;
    tmp[t] = s;
    __syncthreads();
    for (int off = 1; off < 256; off <<= 1) {
        const int u = (t >= off) ? tmp[t - off] : 0;
        __syncthreads();
        tmp[t] += u;
        __syncthreads();
    }
    int p = tmp[t] - s;                         // exclusive prefix
    if (lo + 0 < BUCKETS) { bucketBase[lo + 0] = p; bucketCursor[lo + 0] = p; p += d0; }
    if (lo + 1 < BUCKETS) { bucketBase[lo + 1] = p; bucketCursor[lo + 1] = p; p += d1; }
    if (lo + 2 < BUCKETS) { bucketBase[lo + 2] = p; bucketCursor[lo + 2] = p; p += d2; }
    if (t == 255) bucketBase[BUCKETS] = NNZ;
}

// A3: LDS-stage each chunk grouped by bucket, reserve ranges, copy out
// CONTIGUOUSLY. bucketed[i] = { (rloc<<18)|col , bits(val) }.
__global__ __launch_bounds__(256) void bucketize(
    const int* __restrict__ row, const int* __restrict__ col,
    const float* __restrict__ vals, int* __restrict__ bucketCursor,
    int2* __restrict__ bucketed)
{
    __shared__ int2 stage[CHUNK];               // 38.4 KB
    __shared__ unsigned short bof[CHUNK];       // 9.6 KB
    __shared__ int cnt[BUCKETS], off[BUCKETS], gdst[BUCKETS], cur[BUCKETS];
    __shared__ int tmp[256];
    const int t = threadIdx.x;
    const int base = blockIdx.x * CHUNK;

    for (int b = t; b < BUCKETS; b += 256) { cnt[b] = 0; cur[b] = 0; }
    __syncthreads();
    // pass 0: count
    for (int k = t; k < CHUNK; k += 256)
        atomicAdd(&cnt[row[base + k] / RPB], 1);
    __syncthreads();
    // exclusive scan of cnt -> off (3 slots/thread)
    {
        const int lo = t * 3;
        int d0 = 0, d1 = 0, d2 = 0;
        if (lo + 0 < BUCKETS) d0 = cnt[lo + 0];
        if (lo + 1 < BUCKETS) d1 = cnt[lo + 1];
        if (lo + 2 < BUCKETS) d2 = cnt[lo + 2];
        const int s = d0 + d1 + d2;
        tmp[t] = s;
        __syncthreads();
        for (int o = 1; o < 256; o <<= 1) {
            const int u = (t >= o) ? tmp[t - o] : 0;
            __syncthreads();
            tmp[t] += u;
            __syncthreads();
        }
        int p = tmp[t] - s;
        if (lo + 0 < BUCKETS) { off[lo + 0] = p; p += d0; }
        if (lo + 1 < BUCKETS) { off[lo + 1] = p; p += d1; }
        if (lo + 2 < BUCKETS) { off[lo + 2] = p; p += d2; }
    }
    __syncthreads();
    // reserve global ranges (one atomic per non-empty bucket)
    for (int b = t; b < BUCKETS; b += 256) {
        if (cnt[b]) {
            const int g = atomicAdd(&bucketCursor[b], cnt[b]);
            gdst[b] = g - off[b];
        }
    }
    __syncthreads();
    // pass 1: place into LDS grouped by bucket
    for (int k = t; k < CHUNK; k += 256) {
        const int r = row[base + k];
        const int b = r / RPB;
        const int rank = atomicAdd(&cur[b], 1);
        const int idx  = off[b] + rank;
        stage[idx] = make_int2(((r - b * RPB) << 18) | col[base + k],
                               __float_as_int(vals[base + k]));
        bof[idx] = (unsigned short)b;
    }
    __syncthreads();
    // pass 2: contiguous copy-out (consecutive idx -> consecutive dest)
    for (int k = t; k < CHUNK; k += 256)
        bucketed[gdst[bof[k]] + k] = stage[k];
}

// B: one block per bucket. LDS per-row deg -> scan -> row_ptr (coalesced),
// then scatter csr within the bucket's exclusive 256KB window.
__global__ __launch_bounds__(256) void buildcsr(
    const int2* __restrict__ bucketed, const int* __restrict__ bucketBase,
    int* __restrict__ row_ptr, int2* __restrict__ csr)
{
    __shared__ int deg[RPB], cur[RPB];
    __shared__ int tmp[256];
    const int b = blockIdx.x, t = threadIdx.x;
    const int rlo = b * RPB;
    const int s = bucketBase[b], e = bucketBase[b + 1];

    if (t < RPB) deg[t] = 0;
    __syncthreads();
    for (int i = s + t; i < e; i += 256)
        atomicAdd(&deg[((unsigned)bucketed[i].x) >> 18], 1);
    __syncthreads();
    // exclusive scan of deg[250] over 256 threads
    {
        const int d = (t < RPB) ? deg[t] : 0;
        tmp[t] = d;
        __syncthreads();
        for (int o = 1; o < 256; o <<= 1) {
            const int u = (t >= o) ? tmp[t - o] : 0;
            __syncthreads();
            tmp[t] += u;
            __syncthreads();
        }
        if (t < RPB) {
            const int excl = tmp[t] - d;
            cur[t] = excl;                       // window-relative cursor
            row_ptr[rlo + t] = s + excl;
        }
    }
    if (b == BUCKETS - 1 && t == 0) row_ptr[N_TOTAL] = NNZ;
    __syncthreads();
    for (int i = s + t; i < e; i += 256) {
        const int2 p = bucketed[i];
        const unsigned up = (unsigned)p.x;
        const int rloc = up >> 18;
        const int k = atomicAdd(&cur[rloc], 1);
        csr[s + k] = make_int2((int)(up & COLMASK), p.y);
    }
}

// Assign compact indices to the (deduped) queried rows.
__global__ __launch_bounds__(256) void assign_kernel(
    const int* __restrict__ users, const int* __restrict__ items,
    int* __restrict__ remap, int* __restrict__ list, int* __restrict__ counter)
{
    const int i = blockIdx.x * 256 + threadIdx.x;
    if (i >= 2 * BATCH) return;
    const int r = (i < BATCH) ? users[i] : (N_USERS + items[i - BATCH]);
    if (atomicCAS(&remap[r], -1, -2) == -1) {
        const int idx = atomicAdd(counter, 1);
        list[idx] = r;
        remap[r]  = idx;
    }
}

// ---------------- pull-style SpMM (unchanged, readlane broadcast) ----------------

__device__ __forceinline__ float spmm_row(
    const int2* __restrict__ csr, int start, int end,
    const float* __restrict__ src, int lane)
{
    float p = 0.f;
    for (int base = start; base < end; base += 64) {
        int2 cv = make_int2(0, 0);
        if (base + lane < end) cv = csr[base + lane];
        const int cnt = min(64, end - base);
        for (int ch = 0; ch < cnt; ch += 16) {
            #pragma unroll
            for (int j = 0; j < 16; ++j) {
                const int   c = __builtin_amdgcn_readlane(cv.x, ch + j);
                const float v = __int_as_float(__builtin_amdgcn_readlane(cv.y, ch + j));
                p = fmaf(v, src[(size_t)c * F + lane], p);
            }
        }
    }
    return p;
}

__global__ __launch_bounds__(256) void spmm_layer(
    const int* __restrict__ row_ptr, const int2* __restrict__ csr,
    const float* __restrict__ src, float* __restrict__ dst)
{
    const int r    = blockIdx.x * 4 + (threadIdx.x >> 6);
    const int lane = threadIdx.x & 63;
    if (r >= N_TOTAL) return;
    const float p = spmm_row(csr, row_ptr[r], row_ptr[r + 1], src, lane);
    dst[(size_t)r * F + lane] = p;
}

__global__ __launch_bounds__(256) void spmm_layer2(
    const int* __restrict__ row_ptr, const int2* __restrict__ csr,
    const float* __restrict__ src /*e1*/, float* __restrict__ dst /*e2*/,
    const float* __restrict__ uw, const float* __restrict__ iw,
    const int* __restrict__ remap, float* __restrict__ accC)
{
    const int r    = blockIdx.x * 4 + (threadIdx.x >> 6);
    const int lane = threadIdx.x & 63;
    if (r >= N_TOTAL) return;
    const float p = spmm_row(csr, row_ptr[r], row_ptr[r + 1], src, lane);
    dst[(size_t)r * F + lane] = p;
    const int idx = remap[r];
    if (idx >= 0) {
        const float e0 = (r < N_USERS) ? uw[(size_t)r * F + lane]
                                       : iw[(size_t)(r - N_USERS) * F + lane];
        accC[(size_t)idx * F + lane] = e0 + src[(size_t)r * F + lane];
    }
}

__global__ __launch_bounds__(256) void spmm_layer3(
    const int* __restrict__ row_ptr, const int2* __restrict__ csr,
    const float* __restrict__ src /*e2*/, const int* __restrict__ list,
    const int* __restrict__ counter, float* __restrict__ accC)
{
    const int idx  = blockIdx.x * 4 + (threadIdx.x >> 6);
    const int lane = threadIdx.x & 63;
    if (idx >= *counter) return;
    const int r = list[idx];
    const float p = spmm_row(csr, row_ptr[r], row_ptr[r + 1], src, lane);
    accC[(size_t)idx * F + lane] += src[(size_t)r * F + lane] + p;
}

__global__ __launch_bounds__(256) void batch_dot(
    const float* __restrict__ accC, const int* __restrict__ remap,
    const int* __restrict__ users, const int* __restrict__ items,
    float* __restrict__ out)
{
    const int b    = blockIdx.x * 4 + (threadIdx.x >> 6);
    const int lane = threadIdx.x & 63;
    if (b >= BATCH) return;
    const int iu = remap[users[b]];
    const int ii = remap[N_USERS + items[b]];
    float p = accC[(size_t)iu * F + lane] * accC[(size_t)ii * F + lane];
    #pragma unroll
    for (int off = 32; off > 0; off >>= 1) p += __shfl_down(p, off, 64);
    if (lane == 0) out[b] = p * (1.0f / 16.0f);
}

// ---------------- launch ----------------

extern "C" void kernel_launch(void* const* d_in, const int* in_sizes, int n_in,
                              void* d_out, int out_size, void* d_ws, size_t ws_size,
                              hipStream_t stream)
{
    const float* user_w   = (const float*)d_in[0];
    const float* item_w   = (const float*)d_in[1];
    const float* adj_vals = (const float*)d_in[2];
    const int*   adj_row  = (const int*)d_in[3];
    const int*   adj_col  = (const int*)d_in[4];
    const int*   users    = (const int*)d_in[5];
    const int*   items    = (const int*)d_in[6];
    float*       out      = (float*)d_out;

    const size_t embB  = (size_t)N_TOTAL * F * sizeof(float);   // 38.4 MB
    const size_t csrB  = (size_t)NNZ * sizeof(int2);            // 38.4 MB
    const size_t rpB   = ((size_t)(N_TOTAL + 1) * 4 + 255) & ~(size_t)255;
    const size_t rmB   = ((size_t)N_TOTAL * 4 + 255) & ~(size_t)255;
    const size_t listB = (size_t)2 * BATCH * 4;
    const size_t cntB  = 256;
    const size_t binB  = ((size_t)BUCKETS * 4 + 255) & ~(size_t)255;
    const size_t baseB = ((size_t)(BUCKETS + 1) * 4 + 255) & ~(size_t)255;
    const size_t curB  = binB;
    const size_t accB  = (size_t)2 * BATCH * F * sizeof(float); // 8 MB

    const size_t need = 2 * embB + csrB + rpB + rmB + listB + cntB
                      + binB + baseB + curB + accB;
    if (ws_size < need) {   // defensive: fail visibly, never write OOB
        hipMemsetAsync(d_out, 0, (size_t)out_size * sizeof(float), stream);
        return;
    }

    char* w = (char*)d_ws;
    float* eA        = (float*)w;  w += embB;   // e0 then e2
    float* eB        = (float*)w;  w += embB;   // bucketed edges, then e1
    int2*  csr       = (int2*)w;   w += csrB;
    int*   row_ptr   = (int*)w;    w += rpB;
    int*   remap     = (int*)w;    w += rmB;
    int*   list      = (int*)w;    w += listB;
    int*   counter   = (int*)w;    w += cntB;
    int*   binTotal  = (int*)w;    w += binB;
    int*   bucketBase= (int*)w;    w += baseB;
    int*   bucketCur = (int*)w;    w += curB;
    float* accC      = (float*)w;  w += accB;

    int2* bucketed = (int2*)eB;    // alias: only live before e1 is produced

    // init (ws poisoned 0xAA each call)
    hipMemsetAsync(binTotal, 0, binB, stream);
    hipMemsetAsync(remap, 0xFF, rmB, stream);
    hipMemsetAsync(counter, 0, 4, stream);

    // CSR build: histo -> bin scan -> bucketize (coalesced) -> per-bucket fill
    histo    <<<NCHUNKS, 256, 0, stream>>>(adj_row, binTotal);
    scan_bins<<<1,       256, 0, stream>>>(binTotal, bucketBase, bucketCur);
    bucketize<<<NCHUNKS, 256, 0, stream>>>(adj_row, adj_col, adj_vals,
                                           bucketCur, bucketed);
    buildcsr <<<BUCKETS, 256, 0, stream>>>(bucketed, bucketBase, row_ptr, csr);
    assign_kernel<<<(2 * BATCH + 255) / 256, 256, 0, stream>>>(
        users, items, remap, list, counter);

    // e0 = concat(user_w, item_w)
    hipMemcpyAsync(eA, user_w, (size_t)N_USERS * F * sizeof(float),
                   hipMemcpyDeviceToDevice, stream);
    hipMemcpyAsync(eA + (size_t)N_USERS * F, item_w, (size_t)N_ITEMS * F * sizeof(float),
                   hipMemcpyDeviceToDevice, stream);

    const int rows_blocks = (N_TOTAL + 3) / 4;
    // L1: e1 = A @ e0   (eB's bucketed contents are dead after buildcsr)
    spmm_layer <<<rows_blocks, 256, 0, stream>>>(row_ptr, csr, eA, eB);
    // L2: e2 = A @ e1 (into eA), fused accC = e0 + e1 at queried rows
    spmm_layer2<<<rows_blocks, 256, 0, stream>>>(row_ptr, csr, eB, eA,
                                                 user_w, item_w, remap, accC);
    // L3: queried rows only; accC += e2 + A @ e2
    spmm_layer3<<<(2 * BATCH + 3) / 4, 256, 0, stream>>>(row_ptr, csr, eA,
                                                         list, counter, accC);

    batch_dot<<<(BATCH + 3) / 4, 256, 0, stream>>>(accC, remap, users, items, out);
}